// Round 1
// 34585.352 us; speedup vs baseline: 1.3115x; 1.3115x over previous
//
#include <hip/hip_runtime.h>
#include <stdint.h>

#define BB 512
#define TT 256
#define HH 512
#define NCC 512
#define KIN 272   // SKEL + GEN

typedef float v2f __attribute__((ext_vector_type(2)));

// ---------------- threefry2x32 (JAX-exact, 20 rounds) ----------------
__device__ __forceinline__ void tf_round(uint32_t &x0, uint32_t &x1, int r) {
  x0 += x1;
  x1 = (x1 << r) | (x1 >> (32 - r));
  x1 ^= x0;
}

__device__ __forceinline__ void threefry2x32(uint32_t k0, uint32_t k1,
                                             uint32_t c0, uint32_t c1,
                                             uint32_t &o0, uint32_t &o1) {
  uint32_t ks2 = k0 ^ k1 ^ 0x1BD11BDAu;
  uint32_t x0 = c0 + k0, x1 = c1 + k1;
  tf_round(x0, x1, 13); tf_round(x0, x1, 15); tf_round(x0, x1, 26); tf_round(x0, x1, 6);
  x0 += k1;  x1 += ks2 + 1u;
  tf_round(x0, x1, 17); tf_round(x0, x1, 29); tf_round(x0, x1, 16); tf_round(x0, x1, 24);
  x0 += ks2; x1 += k0 + 2u;
  tf_round(x0, x1, 13); tf_round(x0, x1, 15); tf_round(x0, x1, 26); tf_round(x0, x1, 6);
  x0 += k0;  x1 += k1 + 3u;
  tf_round(x0, x1, 17); tf_round(x0, x1, 29); tf_round(x0, x1, 16); tf_round(x0, x1, 24);
  x0 += k1;  x1 += ks2 + 4u;
  tf_round(x0, x1, 13); tf_round(x0, x1, 15); tf_round(x0, x1, 26); tf_round(x0, x1, 6);
  x0 += ks2; x1 += k0 + 5u;
  o0 = x0; o1 = x1;
}

// ---------------- init: h1T[j][b] = (concat @ Whid.T + b)[j]; xT[k][b]=emb[0][k]
__global__ void __launch_bounds__(256) init_kernel(
    const float* __restrict__ note, const float* __restrict__ genre,
    const float* __restrict__ Whid, const float* __restrict__ bhid,
    const float* __restrict__ emb,
    float* __restrict__ h1T, float* __restrict__ xT, int* __restrict__ tok) {
  int b = blockIdx.x;
  int tid = threadIdx.x;
  __shared__ double u[KIN];
  if (tid < 256) u[tid] = (double)note[b * 256 + tid];
  if (tid < 16)  u[256 + tid] = (double)genre[b * 16 + tid];
  if (tid == 0)  tok[b] = 0;
  __syncthreads();
  for (int j = tid; j < HH; j += 256) {
    double acc = 0.0;
    const float* w = Whid + (size_t)j * KIN;
    #pragma unroll 4
    for (int k = 0; k < KIN; ++k) acc = fma(u[k], (double)w[k], acc);
    h1T[(size_t)j * BB + b] = (float)(acc + (double)bhid[j]);
    xT[(size_t)j * BB + b]  = emb[j];   // emb[0][j] : tok=0 for all b
  }
}

// ---------------- GRU cell: lane = batch row, wave-uniform weights -----------
// Block: 64 batch rows x 8 cols; 256 threads = 4 waves; wave w owns cols {2w,2w+1}.
// All hidden state stored TRANSPOSED: hT[j][b] ([HH][BB]).  x input is k-major xT[k][b].
#define CT 8
#define BT 64
#define KT 32
__global__ void __launch_bounds__(256) gru_kernel(
    const float* __restrict__ Wih, const float* __restrict__ Whh,
    const float* __restrict__ bih, const float* __restrict__ bhh,
    const float* __restrict__ hprevT, float* __restrict__ houtT,
    const float* __restrict__ xT) {
  __shared__ float xs[KT][BT];          // 8 KB
  __shared__ float hs[KT][BT];          // 8 KB
  __shared__ float ws[6][4][KT][2];     // 6 KB : [gate][colpair][k][c]

  int tid  = threadIdx.x;
  int lane = tid & 63;
  int wv   = tid >> 6;                  // 0..3  (wave id -> col pair)
  int j0   = blockIdx.x * CT;
  int b0   = blockIdx.y * BT;

  // x/h staging: 32 k-rows x 64 b; thread t: row tid>>3, 8 floats at bq
  int krow = tid >> 3;
  int bq   = (tid & 7) * 8;
  const float* xsrc = xT     + (size_t)krow * BB + b0 + bq;
  const float* hsrc = hprevT + (size_t)krow * BB + b0 + bq;

  // w staging: 384 float4 tasks; f: kq=f&7, row=f>>3: cc=row&1, pr=(row>>1)&3, g=row>>3
  auto wsrcf = [&](int f) -> const float* {
    int kq = f & 7, row = f >> 3;
    int cc = row & 1, pr = (row >> 1) & 3, g = row >> 3;
    const float* base = (g < 3) ? Wih : Whh;
    int gg = (g < 3) ? g : g - 3;
    return base + ((size_t)gg * HH + j0 + pr * 2 + cc) * HH + kq * 4;
  };
  auto wdstf = [&](int f) -> float* {
    int kq = f & 7, row = f >> 3;
    int cc = row & 1, pr = (row >> 1) & 3, g = row >> 3;
    return &ws[g][pr][kq * 4][cc];
  };
  bool has2 = (tid < 128);
  const float* wsrc1 = wsrcf(tid);
  const float* wsrc2 = has2 ? wsrcf(tid + 256) : wsrc1;
  float* wdst1 = wdstf(tid);
  float* wdst2 = has2 ? wdstf(tid + 256) : wdst1;

  v2f acc[6];
  #pragma unroll
  for (int g = 0; g < 6; ++g) { acc[g][0] = 0.0f; acc[g][1] = 0.0f; }

  // prefetch tile 0
  float4 px0 = *(const float4*)(xsrc);
  float4 px1 = *(const float4*)(xsrc + 4);
  float4 ph0 = *(const float4*)(hsrc);
  float4 ph1 = *(const float4*)(hsrc + 4);
  float4 pw1 = *(const float4*)(wsrc1);
  float4 pw2 = *(const float4*)(wsrc2);

  for (int k0 = 0; k0 < HH; k0 += KT) {
    __syncthreads();   // previous compute done reading LDS
    *(float4*)&xs[krow][bq]     = px0;
    *(float4*)&xs[krow][bq + 4] = px1;
    *(float4*)&hs[krow][bq]     = ph0;
    *(float4*)&hs[krow][bq + 4] = ph1;
    wdst1[0] = pw1.x; wdst1[2] = pw1.y; wdst1[4] = pw1.z; wdst1[6] = pw1.w;
    if (has2) { wdst2[0] = pw2.x; wdst2[2] = pw2.y; wdst2[4] = pw2.z; wdst2[6] = pw2.w; }
    __syncthreads();

    if (k0 + KT < HH) {  // prefetch next tile while computing this one
      xsrc += (size_t)KT * BB; hsrc += (size_t)KT * BB;
      wsrc1 += KT; wsrc2 += KT;
      px0 = *(const float4*)(xsrc);
      px1 = *(const float4*)(xsrc + 4);
      ph0 = *(const float4*)(hsrc);
      ph1 = *(const float4*)(hsrc + 4);
      pw1 = *(const float4*)(wsrc1);
      pw2 = *(const float4*)(wsrc2);
    }

    #pragma unroll 8
    for (int kk = 0; kk < KT; kk += 2) {
      float xa = xs[kk][lane],     ha = hs[kk][lane];
      float xb = xs[kk + 1][lane], hb = hs[kk + 1][lane];
      v2f xa2 = {xa, xa}, xb2 = {xb, xb};
      v2f ha2 = {ha, ha}, hb2 = {hb, hb};
      #pragma unroll
      for (int g = 0; g < 3; ++g) {
        float4 wq = *(const float4*)&ws[g][wv][kk][0];   // wave-uniform broadcast
        v2f lo = {wq.x, wq.y}, hi = {wq.z, wq.w};
        acc[g] = __builtin_elementwise_fma(xa2, lo, acc[g]);
        acc[g] = __builtin_elementwise_fma(xb2, hi, acc[g]);
      }
      #pragma unroll
      for (int g = 3; g < 6; ++g) {
        float4 wq = *(const float4*)&ws[g][wv][kk][0];
        v2f lo = {wq.x, wq.y}, hi = {wq.z, wq.w};
        acc[g] = __builtin_elementwise_fma(ha2, lo, acc[g]);
        acc[g] = __builtin_elementwise_fma(hb2, hi, acc[g]);
      }
    }
  }

  int b = b0 + lane;
  #pragma unroll
  for (int ci = 0; ci < 2; ++ci) {
    int j = j0 + wv * 2 + ci;
    double ir  = (double)acc[0][ci] + (double)bih[j];
    double iz  = (double)acc[1][ci] + (double)bih[HH + j];
    double inn = (double)acc[2][ci] + (double)bih[2 * HH + j];
    double hr  = (double)acc[3][ci] + (double)bhh[j];
    double hz  = (double)acc[4][ci] + (double)bhh[HH + j];
    double hn  = (double)acc[5][ci] + (double)bhh[2 * HH + j];
    double r = 1.0 / (1.0 + exp(-(ir + hr)));
    double z = 1.0 / (1.0 + exp(-(iz + hz)));
    double n = tanh(inn + r * hn);
    double hp = (double)hprevT[(size_t)j * BB + b];
    houtT[(size_t)j * BB + b] = (float)((1.0 - z) * n + z * hp);
  }
}

// ---------------- logits + gumbel-argmax sampling + xT materialization -------
// one block = 2 batch rows, 256 threads; each thread owns 2 columns.
__global__ void __launch_bounds__(256) sample_kernel(
    const float* __restrict__ Wout, const float* __restrict__ bout,
    const float* __restrict__ h2T, float* __restrict__ out0,
    float* __restrict__ out1, int* __restrict__ tok, int t,
    const float* __restrict__ emb, float* __restrict__ xT) {
  __shared__ double hsh[2][HH];
  __shared__ double rs[2][256];
  __shared__ int    ri[2][256];
  int tid = threadIdx.x;
  int b0 = blockIdx.x * 2;

  for (int i = tid; i < 2 * HH; i += 256)
    hsh[i >> 9][i & 511] = (double)h2T[(size_t)(i & 511) * BB + b0 + (i >> 9)];
  __syncthreads();

  uint32_t k1t, k2t;
  threefry2x32(0u, 42u, 0u, (uint32_t)t, k1t, k2t);

  double sbest[2]; int ibest[2];
  #pragma unroll
  for (int half = 0; half < 2; ++half) {
    int cc = tid + half * 256;
    double acc[2] = {0, 0};
    const float* w = Wout + (size_t)cc * HH;
    for (int k = 0; k < HH; k += 4) {
      float4 wv = *(const float4*)(w + k);
      #pragma unroll
      for (int i = 0; i < 2; ++i) {
        acc[i] = fma(hsh[i][k + 0], (double)wv.x, acc[i]);
        acc[i] = fma(hsh[i][k + 1], (double)wv.y, acc[i]);
        acc[i] = fma(hsh[i][k + 2], (double)wv.z, acc[i]);
        acc[i] = fma(hsh[i][k + 3], (double)wv.w, acc[i]);
      }
    }
    double bo = (double)bout[cc];
    #pragma unroll
    for (int i = 0; i < 2; ++i) {
      int b = b0 + i;
      double lg = acc[i] + bo;
      out0[((size_t)b * TT + t) * NCC + cc] = (float)lg;
      uint32_t o0, o1;
      threefry2x32(k1t, k2t, 0u, (uint32_t)(b * NCC + cc), o0, o1);
      uint32_t bits = o0 ^ o1;
      uint32_t ub = bits >> 9;
      float uf;
      if (ub == 0u) uf = 1.17549435e-38f;
      else          uf = __uint_as_float(0x3f800000u | ub) - 1.0f;
      double g = -log(-log((double)uf));
      double s = lg + g;
      if (half == 0) { sbest[i] = s; ibest[i] = cc; }
      else if (s > sbest[i]) { sbest[i] = s; ibest[i] = cc; }
    }
  }
  #pragma unroll
  for (int i = 0; i < 2; ++i) { rs[i][tid] = sbest[i]; ri[i][tid] = ibest[i]; }
  __syncthreads();
  for (int stride = 128; stride > 0; stride >>= 1) {
    if (tid < stride) {
      #pragma unroll
      for (int i = 0; i < 2; ++i) {
        double so = rs[i][tid + stride]; int io = ri[i][tid + stride];
        double sm = rs[i][tid];          int im = ri[i][tid];
        if (so > sm || (so == sm && io < im)) { rs[i][tid] = so; ri[i][tid] = io; }
      }
    }
    __syncthreads();
  }
  if (tid < 2) {
    int b = b0 + tid;
    int idx = ri[tid][0];
    tok[b] = idx;
    out1[(size_t)b * TT + t] = (float)idx;
  }
  // materialize next-step xT[:, b] = emb[tok[b], :] (bit-exact copy of emb row)
  #pragma unroll
  for (int i = 0; i < 2; ++i) {
    int row = ri[i][0];
    int b = b0 + i;
    for (int k = tid; k < HH; k += 256)
      xT[(size_t)k * BB + b] = emb[(size_t)row * HH + k];
  }
}

// ---------------- host launch ----------------
extern "C" void kernel_launch(void* const* d_in, const int* in_sizes, int n_in,
                              void* d_out, int out_size, void* d_ws, size_t ws_size,
                              hipStream_t stream) {
  const float* note  = (const float*)d_in[1];
  const float* genre = (const float*)d_in[2];
  const float* Whid  = (const float*)d_in[3];
  const float* bhid  = (const float*)d_in[4];
  const float* emb   = (const float*)d_in[5];
  const float* Wih1  = (const float*)d_in[6];
  const float* Whh1  = (const float*)d_in[7];
  const float* bih1  = (const float*)d_in[8];
  const float* bhh1  = (const float*)d_in[9];
  const float* Wih2  = (const float*)d_in[10];
  const float* Whh2  = (const float*)d_in[11];
  const float* bih2  = (const float*)d_in[12];
  const float* bhh2  = (const float*)d_in[13];
  const float* Wout  = (const float*)d_in[14];
  const float* bout  = (const float*)d_in[15];

  float* out0 = (float*)d_out;                      // [B, T, NC] logits
  float* out1 = out0 + (size_t)BB * TT * NCC;       // [B, T] tokens (as float)

  char* wsp = (char*)d_ws;
  float* h1a = (float*)wsp; wsp += (size_t)BB * HH * sizeof(float);
  float* h1b = (float*)wsp; wsp += (size_t)BB * HH * sizeof(float);
  float* h2a = (float*)wsp; wsp += (size_t)BB * HH * sizeof(float);
  float* h2b = (float*)wsp; wsp += (size_t)BB * HH * sizeof(float);
  float* xT  = (float*)wsp; wsp += (size_t)HH * BB * sizeof(float);
  int* tok = (int*)wsp;

  init_kernel<<<BB, 256, 0, stream>>>(note, genre, Whid, bhid, emb, h1a, xT, tok);

  float* c1 = h1a;
  float* c2 = h2a;
  dim3 ggrid(HH / CT, BB / BT);  // 64 x 8 = 512 blocks (2 per CU)
  for (int t = 0; t < TT; ++t) {
    float* n1 = (c1 == h1a) ? h1b : h1a;
    float* n2 = (c2 == h2a) ? h2b : h2a;
    gru_kernel<<<ggrid, 256, 0, stream>>>(Wih1, Whh1, bih1, bhh1, c1, n1, xT);
    const float* hsrc2 = (t == 0) ? (const float*)n1 : (const float*)c2;
    gru_kernel<<<ggrid, 256, 0, stream>>>(Wih2, Whh2, bih2, bhh2, hsrc2, n2, n1);
    sample_kernel<<<BB / 2, 256, 0, stream>>>(Wout, bout, n2, out0, out1, tok, t,
                                              emb, xT);
    c1 = n1;
    c2 = n2;
  }
}